// Round 7
// baseline (762.812 us; speedup 1.0000x reference)
//
#include <hip/hip_runtime.h>
#include <cstdint>
#include <cstddef>

#define NN 50000
#define EE 1600000
#define SCAN_BLOCKS ((NN + 255) / 256)   // 196

typedef __attribute__((ext_vector_type(8))) short short8;
typedef __attribute__((ext_vector_type(8))) unsigned short ushort8;
typedef __attribute__((ext_vector_type(4))) float float4v;

__device__ __forceinline__ float bf2f(unsigned short u) {
    union { unsigned int i; float f; } v; v.i = ((unsigned int)u) << 16; return v.f;
}
__device__ __forceinline__ unsigned short f2bf(float f) {
    union { float f; unsigned int i; } v; v.f = f;
    unsigned int r = v.i + 0x7FFF + ((v.i >> 16) & 1);   // RNE
    return (unsigned short)(r >> 16);
}

// ---------------- fp32 -> bf16 convert ----------------
__global__ __launch_bounds__(256) void cvt_kernel(const float* __restrict__ in,
                                                  unsigned short* __restrict__ out, int n) {
    int i = (blockIdx.x * 256 + threadIdx.x) * 4;
    if (i + 3 >= n) {
        for (int k = i; k < n; k++) out[k] = f2bf(in[k]);
        return;
    }
    float4 v = *(const float4*)(in + i);
    ushort4 o;
    o.x = f2bf(v.x); o.y = f2bf(v.y); o.z = f2bf(v.z); o.w = f2bf(v.w);
    *(ushort4*)(out + i) = o;
}

__global__ __launch_bounds__(256) void cvt_w_kernel(
    const float* __restrict__ w1, unsigned short* __restrict__ o1,   // 32768
    const float* __restrict__ w2, unsigned short* __restrict__ o2,   // 65536
    const float* __restrict__ w3, unsigned short* __restrict__ o3)   // 65536
{
    int i = (blockIdx.x * 256 + threadIdx.x) * 4;
    const float* in; unsigned short* out;
    if (i < 32768) { in = w1; out = o1; }
    else if (i < 32768 + 65536) { in = w2; out = o2; i -= 32768; }
    else { in = w3; out = o3; i -= 32768 + 65536; }
    float4 v = *(const float4*)(in + i);
    ushort4 o;
    o.x = f2bf(v.x); o.y = f2bf(v.y); o.z = f2bf(v.z); o.w = f2bf(v.w);
    *(ushort4*)(out + i) = o;
}

// ---------------- CSR build: histogram -> 3-phase scan -> fused bin ----------------
__global__ __launch_bounds__(256) void hist_kernel(const int* __restrict__ dst,
                                                   int* __restrict__ deg, int E) {
    int e = blockIdx.x * 256 + threadIdx.x;
    if (e >= E) return;
    int d = dst[e];
    if ((unsigned)d < NN) atomicAdd(&deg[d], 1);
}

__global__ __launch_bounds__(256) void scan1_kernel(const int* __restrict__ deg,
                                                    int* __restrict__ bsum) {
    int i = blockIdx.x * 256 + threadIdx.x;
    int v = (i < NN) ? deg[i] : 0;
    #pragma unroll
    for (int off = 32; off > 0; off >>= 1) v += __shfl_down(v, off, 64);
    __shared__ int ws[4];
    if ((threadIdx.x & 63) == 0) ws[threadIdx.x >> 6] = v;
    __syncthreads();
    if (threadIdx.x == 0) bsum[blockIdx.x] = ws[0] + ws[1] + ws[2] + ws[3];
}

__global__ __launch_bounds__(256) void scan2_kernel(const int* __restrict__ bsum,
                                                    int* __restrict__ boff,
                                                    int* __restrict__ rowptr) {
    __shared__ int s[256];
    int t = threadIdx.x;
    int v = (t < SCAN_BLOCKS) ? bsum[t] : 0;
    s[t] = v;
    __syncthreads();
    #pragma unroll
    for (int off = 1; off < 256; off <<= 1) {
        int val = (t >= off) ? s[t - off] : 0;
        __syncthreads();
        s[t] += val;
        __syncthreads();
    }
    if (t < SCAN_BLOCKS) boff[t] = s[t] - v;
    if (t == 255) rowptr[NN] = s[255];
}

__global__ __launch_bounds__(256) void scan3_kernel(const int* __restrict__ deg,
                                                    const int* __restrict__ boff,
                                                    int* __restrict__ rowptr,
                                                    int* __restrict__ cursor) {
    __shared__ int s[256];
    int t = threadIdx.x;
    int i = blockIdx.x * 256 + t;
    int v = (i < NN) ? deg[i] : 0;
    s[t] = v;
    __syncthreads();
    #pragma unroll
    for (int off = 1; off < 256; off <<= 1) {
        int val = (t >= off) ? s[t - off] : 0;
        __syncthreads();
        s[t] += val;
        __syncthreads();
    }
    int excl = s[t] - v + boff[blockIdx.x];
    if (i < NN) { rowptr[i] = excl; cursor[i] = excl; }
}

// ew inline; ONE packed 4B record/edge: src(lo16) | bf16 w(hi16)
__global__ __launch_bounds__(256) void bin_fused(
    const int* __restrict__ src, const int* __restrict__ dst,
    const float* __restrict__ ea, int* __restrict__ cursor,
    unsigned int* __restrict__ recs, int E)
{
    int e = blockIdx.x * 256 + threadIdx.x;
    if (e >= E) return;
    const float4* p = (const float4*)(ea + (size_t)e * 8);
    float4 a = p[0], b = p[1];
    float w = (a.x + a.y + a.z + a.w + b.x + b.y + b.z + b.w) * 0.125f;
    int d = dst[e], s = src[e];
    if ((unsigned)d >= NN || (unsigned)s >= NN) return;
    int pos = atomicAdd(&cursor[d], 1);
    recs[pos] = (unsigned int)s | ((unsigned int)f2bf(w) << 16);
}

// ---------------- fused layer: gather 64-node tile -> LDS -> MFMA GEMM ----------------
// Block = 256 thr (4 waves), owns 64 dst nodes. Phase 1: each wave gathers 16
// nodes (half-wave per edge for CIN=256, quarter-wave for CIN=128) into LDS.
// Phase 2: 64x256 GEMM vs W[256,CIN]^T from L2, BN/ReLU epilogue.
// MODE 1: BN+ReLU, bf16 out; MODE 0: bias only, fp32 out.
template <int CIN, bool HASW, int MODE>
__global__ __launch_bounds__(256) void layer_fused(
    const unsigned short* __restrict__ h, const int* __restrict__ rowptr,
    const unsigned int* __restrict__ recs, const unsigned short* __restrict__ W,
    const float* __restrict__ bias,
    const float* __restrict__ gamma, const float* __restrict__ beta,
    const float* __restrict__ mean, const float* __restrict__ var,
    void* __restrict__ out)
{
    constexpr int S = (CIN == 256) ? 264 : 136;   // LDS row stride (shorts): 16B-aligned, bank-safe
    __shared__ unsigned short As[64 * S];

    const int tid  = threadIdx.x;
    const int wave = tid >> 6;
    const int lane = tid & 63;
    const int node0 = blockIdx.x * 64;

    // ---- phase 1: gather ----
    for (int t = 0; t < 16; t++) {
        int local = wave * 16 + t;
        int node = node0 + local;
        if (node >= NN) break;
        int beg = rowptr[node], end = rowptr[node + 1];
        float a[8] = {0.f, 0.f, 0.f, 0.f, 0.f, 0.f, 0.f, 0.f};

        if (CIN == 256) {
            const int half = lane >> 5;
            const int l32  = lane & 31;
            int j = beg;
            for (; j + 16 <= end; j += 16) {
                unsigned int r[8]; ushort8 v[8];
                #pragma unroll
                for (int u = 0; u < 8; u++) r[u] = recs[j + 2 * u + half];
                #pragma unroll
                for (int u = 0; u < 8; u++)
                    v[u] = *(const ushort8*)(h + (size_t)(r[u] & 0xFFFF) * 256 + l32 * 8);
                #pragma unroll
                for (int u = 0; u < 8; u++) {
                    float w = HASW ? bf2f((unsigned short)(r[u] >> 16)) : 1.f;
                    #pragma unroll
                    for (int k = 0; k < 8; k++) a[k] += w * bf2f(v[u][k]);
                }
            }
            for (; j < end; j += 2) {
                int idx = j + half;
                unsigned int r = recs[idx < end ? idx : end - 1];
                float w = (idx < end) ? (HASW ? bf2f((unsigned short)(r >> 16)) : 1.f) : 0.f;
                ushort8 v = *(const ushort8*)(h + (size_t)(r & 0xFFFF) * 256 + l32 * 8);
                #pragma unroll
                for (int k = 0; k < 8; k++) a[k] += w * bf2f(v[k]);
            }
            #pragma unroll
            for (int k = 0; k < 8; k++) a[k] += __shfl_xor(a[k], 32, 64);
            if (half == 0) {
                ushort8 o;
                #pragma unroll
                for (int k = 0; k < 8; k++) o[k] = f2bf(a[k]);
                *(ushort8*)(&As[local * S + l32 * 8]) = o;
            }
        } else {  // CIN == 128
            const int quar = lane >> 4;
            const int l16  = lane & 15;
            int j = beg;
            for (; j + 16 <= end; j += 16) {
                unsigned int r[4]; ushort8 v[4];
                #pragma unroll
                for (int u = 0; u < 4; u++) r[u] = recs[j + 4 * u + quar];
                #pragma unroll
                for (int u = 0; u < 4; u++)
                    v[u] = *(const ushort8*)(h + (size_t)(r[u] & 0xFFFF) * 128 + l16 * 8);
                #pragma unroll
                for (int u = 0; u < 4; u++) {
                    float w = HASW ? bf2f((unsigned short)(r[u] >> 16)) : 1.f;
                    #pragma unroll
                    for (int k = 0; k < 8; k++) a[k] += w * bf2f(v[u][k]);
                }
            }
            for (; j < end; j += 4) {
                int idx = j + quar;
                unsigned int r = recs[idx < end ? idx : end - 1];
                float w = (idx < end) ? (HASW ? bf2f((unsigned short)(r >> 16)) : 1.f) : 0.f;
                ushort8 v = *(const ushort8*)(h + (size_t)(r & 0xFFFF) * 128 + l16 * 8);
                #pragma unroll
                for (int k = 0; k < 8; k++) a[k] += w * bf2f(v[k]);
            }
            #pragma unroll
            for (int k = 0; k < 8; k++) {
                a[k] += __shfl_xor(a[k], 16, 64);
                a[k] += __shfl_xor(a[k], 32, 64);
            }
            if (quar == 0) {
                ushort8 o;
                #pragma unroll
                for (int k = 0; k < 8; k++) o[k] = f2bf(a[k]);
                *(ushort8*)(&As[local * S + l16 * 8]) = o;
            }
        }
    }
    __syncthreads();

    // ---- phase 2: 64x256 GEMM, wave w owns cols [w*64, w*64+64) ----
    const int quad = lane >> 4;
    const int l16  = lane & 15;
    const int col0 = wave * 64;

    float4v acc[4][4] = {};
    for (int k0 = 0; k0 < CIN; k0 += 32) {
        const int ka = k0 + quad * 8;
        short8 af[4], bf[4];
        #pragma unroll
        for (int i = 0; i < 4; i++) {
            af[i] = *(const short8*)(&As[(i * 16 + l16) * S + ka]);
            bf[i] = *(const short8*)(W + (size_t)(col0 + i * 16 + l16) * CIN + ka);
        }
        #pragma unroll
        for (int mi = 0; mi < 4; mi++)
            #pragma unroll
            for (int ni = 0; ni < 4; ni++)
                acc[mi][ni] = __builtin_amdgcn_mfma_f32_16x16x32_bf16(
                    af[mi], bf[ni], acc[mi][ni], 0, 0, 0);
    }

    float cb[4], cmu[4], cinv[4], cbe[4];
    #pragma unroll
    for (int ni = 0; ni < 4; ni++) {
        int gc = col0 + ni * 16 + l16;
        cb[ni] = bias[gc];
        if (MODE == 1) {
            cmu[ni]  = mean[gc];
            cinv[ni] = gamma[gc] * rsqrtf(var[gc] + 1e-5f);
            cbe[ni]  = beta[gc];
        }
    }
    #pragma unroll
    for (int mi = 0; mi < 4; mi++) {
        #pragma unroll
        for (int reg = 0; reg < 4; reg++) {
            int gr = node0 + mi * 16 + quad * 4 + reg;
            if (gr >= NN) continue;
            #pragma unroll
            for (int ni = 0; ni < 4; ni++) {
                int gc = col0 + ni * 16 + l16;
                float v = acc[mi][ni][reg] + cb[ni];
                if (MODE == 1) {
                    v = (v - cmu[ni]) * cinv[ni] + cbe[ni];
                    v = fmaxf(v, 0.f);
                    ((unsigned short*)out)[(size_t)gr * 256 + gc] = f2bf(v);
                } else {
                    ((float*)out)[(size_t)gr * 256 + gc] = v;
                }
            }
        }
    }
}

extern "C" void kernel_launch(void* const* d_in, const int* in_sizes, int n_in,
                              void* d_out, int out_size, void* d_ws, size_t ws_size,
                              hipStream_t stream) {
    const float* x   = (const float*)d_in[0];
    const int*   ei  = (const int*)d_in[1];   // [2, E] int32
    const float* ea  = (const float*)d_in[2];
    const float* W1  = (const float*)d_in[3];
    const float* b1  = (const float*)d_in[4];
    const float* g1  = (const float*)d_in[5];
    const float* be1 = (const float*)d_in[6];
    const float* m1  = (const float*)d_in[7];
    const float* v1  = (const float*)d_in[8];
    const float* W2  = (const float*)d_in[9];
    const float* b2  = (const float*)d_in[10];
    const float* g2  = (const float*)d_in[11];
    const float* be2 = (const float*)d_in[12];
    const float* m2  = (const float*)d_in[13];
    const float* v2  = (const float*)d_in[14];
    const float* W3  = (const float*)d_in[15];
    const float* b3  = (const float*)d_in[16];

    const int* src = ei;
    const int* dst = ei + EE;

    // workspace carve-up (256B-aligned segments)
    char* p = (char*)d_ws;
    auto alloc = [&](size_t bytes) { char* r = p; p += (bytes + 255) & ~255ULL; return r; };
    int*            rowptr = (int*)alloc((NN + 1) * 4);
    int*            cursor = (int*)alloc(NN * 4);
    int*            bsum   = (int*)alloc(SCAN_BLOCKS * 4);
    int*            boff   = (int*)alloc(SCAN_BLOCKS * 4);
    unsigned int*   recs   = (unsigned int*)alloc((size_t)EE * 4);
    unsigned short* xb     = (unsigned short*)alloc((size_t)NN * 128 * 2);
    unsigned short* W1b    = (unsigned short*)alloc(256 * 128 * 2);
    unsigned short* W2b    = (unsigned short*)alloc(256 * 256 * 2);
    unsigned short* W3b    = (unsigned short*)alloc(256 * 256 * 2);
    unsigned short* hA     = (unsigned short*)alloc((size_t)NN * 256 * 2);
    unsigned short* hB     = (unsigned short*)alloc((size_t)NN * 256 * 2);
    float*          out    = (float*)d_out;

    const int eblocks = (EE + 255) / 256;
    const int lblocks = (NN + 63) / 64;   // 782

    // converts
    cvt_kernel<<<(NN * 128 / 4 + 255) / 256, 256, 0, stream>>>(x, xb, NN * 128);
    cvt_w_kernel<<<(32768 + 65536 + 65536) / 4 / 256, 256, 0, stream>>>(
        W1, W1b, W2, W2b, W3, W3b);

    // CSR build: hist -> 3-phase scan -> fused bin (cursor doubles as histogram)
    hipMemsetAsync(cursor, 0, NN * sizeof(int), stream);
    hist_kernel<<<eblocks, 256, 0, stream>>>(dst, cursor, EE);
    scan1_kernel<<<SCAN_BLOCKS, 256, 0, stream>>>(cursor, bsum);
    scan2_kernel<<<1, 256, 0, stream>>>(bsum, boff, rowptr);
    scan3_kernel<<<SCAN_BLOCKS, 256, 0, stream>>>(cursor, boff, rowptr, cursor);
    bin_fused<<<eblocks, 256, 0, stream>>>(src, dst, ea, cursor, recs, EE);

    // ---- layer 1: gather x (C=128) + GEMM W1 + BN1 + ReLU -> hA (bf16) ----
    layer_fused<128, true, 1><<<lblocks, 256, 0, stream>>>(
        xb, rowptr, recs, W1b, b1, g1, be1, m1, v1, hA);

    // ---- layer 2: gather hA (C=256) + GEMM W2 + BN2 + ReLU -> hB (bf16) ----
    layer_fused<256, true, 1><<<lblocks, 256, 0, stream>>>(
        hA, rowptr, recs, W2b, b2, g2, be2, m2, v2, hB);

    // ---- layer 3: gather hB (C=256, no weight) + GEMM W3 + bias -> out (fp32) ----
    layer_fused<256, false, 0><<<lblocks, 256, 0, stream>>>(
        hB, rowptr, recs, W3b, b3, nullptr, nullptr, nullptr, nullptr, out);
}